// Round 10
// baseline (270.889 us; speedup 1.0000x reference)
//
#include <hip/hip_runtime.h>
#include <hip/hip_bf16.h>

#define BN 8192
#define DIM 512
#define NB  64            // BN / 128 block-rows
#define NTILES 2080       // NB*(NB+1)/2 upper-triangle tiles
#define PBLK 512          // persistent blocks (2 per CU)
#define EPSF 1e-8f

using v8i   = __attribute__((ext_vector_type(8))) int;
using v4i   = __attribute__((ext_vector_type(4))) int;
using f32x4 = __attribute__((ext_vector_type(4))) float;
using f32x2 = __attribute__((ext_vector_type(2))) float;

// Native exp2 (single v_exp_f32); fallback keeps exact semantics.
#if __has_builtin(__builtin_amdgcn_exp2f)
#define EXP2F(x) __builtin_amdgcn_exp2f(x)
#else
#define EXP2F(x) __expf((x) * 0.69314718055994531f)
#endif

__device__ __forceinline__ f32x2 shfl_xor2(f32x2 v, int m) {
    f32x2 r;
    r[0] = __shfl_xor(v[0], m, 64);
    r[1] = __shfl_xor(v[1], m, 64);
    return r;
}

// Async global->LDS, 16 B per lane, dest = uniform base + lane*16.
__device__ __forceinline__ void async_copy16(const void* g, void* l) {
    __builtin_amdgcn_global_load_lds(
        (const __attribute__((address_space(1))) void*)g,
        (__attribute__((address_space(3))) void*)l,
        16, 0, 0);
}

// Triangular decode: tile index -> (bi, bj), upper triangle.
__device__ __forceinline__ void decode_tile(int t, int& bi, int& bj) {
    int b = (int)(64.5f - sqrtf(64.5f * 64.5f - 2.0f * (float)t));
    while (64 * (b + 1) - ((b + 1) * b) / 2 <= t) ++b;
    while (64 * b - (b * (b - 1)) / 2 > t) --b;
    bi = b;
    bj = b + (t - (64 * b - (b * (b - 1)) / 2));
}

// One wave per row: L2-normalize, x4 pre-scale, fp8 e4m3; out[0] and the
// global label-count array zeroed by block 0 (cnt is filled by gemm's diag
// tiles, read by finalize -- all stream-ordered).
__global__ __launch_bounds__(256) void normalize_kernel(
        const float* __restrict__ emb, unsigned char* __restrict__ E,
        int* __restrict__ cntG, float* __restrict__ out) {
    if (blockIdx.x == 0) {
        if (threadIdx.x == 0) out[0] = 0.f;
        if (threadIdx.x < 128) cntG[threadIdx.x] = 0;
    }
    int lane = threadIdx.x & 63;
    int row  = blockIdx.x * 4 + (threadIdx.x >> 6);
    const float4* src = (const float4*)(emb + (size_t)row * DIM);
    float4 a = src[lane];
    float4 b = src[lane + 64];
    float ss = a.x*a.x + a.y*a.y + a.z*a.z + a.w*a.w
             + b.x*b.x + b.y*b.y + b.z*b.z + b.w*b.w;
    #pragma unroll
    for (int m = 1; m < 64; m <<= 1) ss += __shfl_xor(ss, m, 64);
    float s4 = 4.0f / fmaxf(sqrtf(ss), 1e-12f);
    int pa = __builtin_amdgcn_cvt_pk_fp8_f32(a.x*s4, a.y*s4, 0, false);
    pa     = __builtin_amdgcn_cvt_pk_fp8_f32(a.z*s4, a.w*s4, pa, true);
    int pb = __builtin_amdgcn_cvt_pk_fp8_f32(b.x*s4, b.y*s4, 0, false);
    pb     = __builtin_amdgcn_cvt_pk_fp8_f32(b.z*s4, b.w*s4, pb, true);
    unsigned char* rowp = E + (size_t)row * DIM;
    ((unsigned*)rowp)[lane]         = (unsigned)pa;
    ((unsigned*)(rowp + 256))[lane] = (unsigned)pb;
}

// PERSISTENT upper-triangle GEMM+epilogue. 512 blocks (2/CU), each walks
// tiles t = bid, bid+512, ... (~4 tiles). fp8 MX MFMA 16x16x128; 8 waves,
// wave (vC,vQ) owns 64x32.
// Tile pipeline (the round-10 change): plane k of the CURRENT tile is dead
// after k-step k, so k-step k = { ds_read plane k -> lgkmcnt(0) ->
// s_barrier (all waves' reads certified) -> stage plane k of tile t+512
// into the SAME 16 KB -> MFMA }. Next-tile staging overlaps the whole
// current tile's compute+epilogue; only tile 0 pays an exposed prologue
// convoy (vs one per block x 2080 blocks before). The per-k barrier waits
// only on own LDS reads (~150cy, uniform) -- never on vmcnt.
// Epilogue: in-register shfl_xor butterfly (r9-proven numerics) -> tiny
// rowSum[4][128]/colSum[2][128] LDS (6 KB) -> one barrier -> plain
// coalesced stores into P/N [NB][BN] (NO global atomics -- r9's 18us
// mistake). Boundary: stores -> next labels/B0 -> vmcnt(4) -> barrier.
// LDS total ~73 KB -> 2 blocks/CU; regs ~64+32 -> 4 waves/SIMD.
__global__ __launch_bounds__(512, 4) void gemm_epi_kernel(
        const unsigned char* __restrict__ E, const int* __restrict__ labels,
        int* __restrict__ cntG, float* __restrict__ P, float* __restrict__ N) {
    __shared__ __attribute__((aligned(16))) unsigned char As[65536];
    __shared__ float2 rowSum[4][128];    // 4 KB, slot = vQ
    __shared__ float2 colSum[2][128];    // 2 KB, slot = vC
    __shared__ int labI[128];
    __shared__ int labJ[128];

    const int tid  = threadIdx.x;
    const int wave = tid >> 6;          // 0..7
    const int lane = tid & 63;
    const int quad = lane >> 4;
    const int lrow = lane & 15;
    const int vC   = wave >> 2;         // i-half   (0..1)
    const int vQ   = wave & 3;          // j-quarter(0..3)
    const int i_w  = vC * 64;
    const int j_w  = vQ * 32;
    const int stRow = lane >> 3;
    const int stChk = (lane & 7) ^ stRow;
    const int sw    = lrow & 7;
    const bool bit0 = (lrow & 1) != 0;
    const bool bit1 = (lrow & 2) != 0;

    int t = blockIdx.x;
    int bi, bj;
    decode_tile(t, bi, bj);
    bool diag = (bi == bj);
    int i0 = bi * 128, j0 = bj * 128;

    if (tid < 128)        labI[tid]       = labels[i0 + tid];
    else if (tid < 256)   labJ[tid - 128] = labels[j0 + tid - 128];
    if (diag && tid < 128) atomicAdd(&cntG[labels[i0 + tid]], 1);

    const unsigned char* gA = E + (size_t)(i0 + wave * 16 + stRow) * DIM
                                + stChk * 16;
    const v4i* bptr[2];
    #pragma unroll
    for (int tj = 0; tj < 2; ++tj)
        bptr[tj] = (const v4i*)(E +
            (size_t)(j0 + j_w + tj * 16 + lrow) * DIM + quad * 32);

    // Prologue (tile 0 only pays this exposed): stage all 4 planes, B0,
    // vmcnt(4) (staging+atomic retired, B0 in flight), lgkm drain, barrier.
    #pragma unroll
    for (int c = 0; c < 4; ++c)
        #pragma unroll
        for (int h = 0; h < 2; ++h)
            async_copy16(gA + (size_t)h * 8 * DIM + c * 128,
                         As + (size_t)c * 16384
                            + (size_t)(wave * 16 + h * 8) * 128);
    __builtin_amdgcn_sched_barrier(0);
    v8i bf[2][2];
    #pragma unroll
    for (int tj = 0; tj < 2; ++tj) {
        ((v4i*)&bf[0][tj])[0] = bptr[tj][0];
        ((v4i*)&bf[0][tj])[1] = bptr[tj][1];
    }
    asm volatile("s_waitcnt vmcnt(4) lgkmcnt(0)" ::: "memory");
    __builtin_amdgcn_s_barrier();
    __builtin_amdgcn_sched_barrier(0);

    while (true) {
        const bool hasNext = (t + PBLK < NTILES);
        int t2 = 0, bi2 = 0, bj2 = 0, i02 = 0, j02 = 0;
        const unsigned char* gA2 = nullptr;
        if (hasNext) {
            t2 = t + PBLK;
            decode_tile(t2, bi2, bj2);
            i02 = bi2 * 128; j02 = bj2 * 128;
            gA2 = E + (size_t)(i02 + wave * 16 + stRow) * DIM + stChk * 16;
        }

        f32x4 acc[4][2];
        #pragma unroll
        for (int a = 0; a < 4; ++a)
            #pragma unroll
            for (int b = 0; b < 2; ++b)
                acc[a][b] = (f32x4){0.f, 0.f, 0.f, 0.f};

        #pragma unroll
        for (int k = 0; k < 4; ++k) {
            const int cur = k & 1;
            unsigned char* bufC = As + (size_t)k * 16384;
            v8i af[4];
            #pragma unroll
            for (int ti = 0; ti < 4; ++ti) {
                int r = i_w + ti * 16 + lrow;
                const v4i* rp = (const v4i*)(bufC + (size_t)r * 128);
                ((v4i*)&af[ti])[0] = rp[(quad * 2) ^ sw];
                ((v4i*)&af[ti])[1] = rp[(quad * 2 + 1) ^ sw];
            }
            // Read-protect barrier: every wave's reads of plane k retired
            // before any wave overwrites it with tile t+PBLK's plane k.
            asm volatile("s_waitcnt lgkmcnt(0)" ::: "memory");
            __builtin_amdgcn_sched_barrier(0);
            __builtin_amdgcn_s_barrier();
            __builtin_amdgcn_sched_barrier(0);
            if (hasNext) {
                #pragma unroll
                for (int h = 0; h < 2; ++h)
                    async_copy16(gA2 + (size_t)h * 8 * DIM + k * 128,
                                 bufC + (size_t)(wave * 16 + h * 8) * 128);
                __builtin_amdgcn_sched_barrier(0);
            }
            if (k < 3) {                  // prefetch next k's B (reg dep)
                #pragma unroll
                for (int tj = 0; tj < 2; ++tj) {
                    ((v4i*)&bf[cur ^ 1][tj])[0] = bptr[tj][(k + 1) * 8];
                    ((v4i*)&bf[cur ^ 1][tj])[1] = bptr[tj][(k + 1) * 8 + 1];
                }
            }
            #pragma unroll
            for (int ti = 0; ti < 4; ++ti)
                #pragma unroll
                for (int tj = 0; tj < 2; ++tj)
                    acc[ti][tj] =
                        __builtin_amdgcn_mfma_scale_f32_16x16x128_f8f6f4(
                            af[ti], bf[cur][tj], acc[ti][tj],
                            0, 0,                 // fp8 e4m3 / e4m3
                            0, 0x7F7F7F7F,        // A scale = 1.0
                            0, 0x7F7F7F7F);       // B scale = 1.0
        }

        // Epilogue, per-wave butterfly (r9-proven). C/D: col = lane&15,
        // row = quad*4 + reg. acc = 16*S; w = exp(S-1) = exp2(acc*K1+K2).
        const float K1 = 0.0901619783824569f;    // log2(e)/16
        const float K2 = -1.4426950408889634f;   // -log2(e)
        f32x2 csum[2];
        csum[0] = (f32x2){0.f, 0.f};
        csum[1] = (f32x2){0.f, 0.f};

        #pragma unroll
        for (int ti = 0; ti < 4; ++ti) {
            f32x2 pn[4];
            #pragma unroll
            for (int reg = 0; reg < 4; ++reg) {
                int irow = i_w + ti * 16 + quad * 4 + reg;
                int li   = labI[irow];
                float pos = 0.f, ts = 0.f, sf = 0.f;
                #pragma unroll
                for (int tj = 0; tj < 2; ++tj) {
                    int jcol = j_w + tj * 16 + lrow;
                    float w  = EXP2F(fmaf(acc[ti][tj][reg], K1, K2));
                    float ws = (li == labJ[jcol]) ? w : 0.f;
                    pos += ws;  ts += w;
                    if (diag) sf += (irow == jcol) ? w : 0.f;
                    csum[tj][0] += ws;
                    csum[tj][1] += w;
                }
                pn[reg] = (f32x2){pos - sf, ts - pos};  // (pos\self, neg)
            }
            // Butterfly: mask-1 combines reg pairs (keep reg bit0 == bit0),
            // mask-2 (keep reg bit1 == bit1), then plain 4/8 reduce.
            f32x2 s01 = bit0 ? pn[0] : pn[1];
            f32x2 q0  = (bit0 ? pn[1] : pn[0]) + shfl_xor2(s01, 1);
            f32x2 s23 = bit0 ? pn[2] : pn[3];
            f32x2 q1  = (bit0 ? pn[3] : pn[2]) + shfl_xor2(s23, 1);
            f32x2 sB  = bit1 ? q0 : q1;
            f32x2 v   = (bit1 ? q1 : q0) + shfl_xor2(sB, 2);
            v += shfl_xor2(v, 4);
            v += shfl_xor2(v, 8);
            if (lrow < 4) {
                int irow = i_w + ti * 16 + quad * 4 + lrow;
                rowSum[vQ][irow] = (float2){v[0], v[1]};
            }
        }
        if (!diag) {
            #pragma unroll
            for (int tj = 0; tj < 2; ++tj) {
                f32x2 cv = csum[tj];
                cv += shfl_xor2(cv, 16);
                cv += shfl_xor2(cv, 32);
                if (quad == 0) {
                    int jcol = j_w + tj * 16 + lrow;
                    colSum[vC][jcol] = (float2){cv[0], cv[1] - cv[0]};
                }
            }
        }
        asm volatile("s_waitcnt lgkmcnt(0)" ::: "memory");
        __builtin_amdgcn_sched_barrier(0);
        __builtin_amdgcn_s_barrier();
        __builtin_amdgcn_sched_barrier(0);

        // Combine + coalesced stores (one writer per element, no atomics).
        if (tid < 128) {
            float2 r0 = rowSum[0][tid], r1 = rowSum[1][tid];
            float2 r2 = rowSum[2][tid], r3 = rowSum[3][tid];
            P[(size_t)bj * BN + i0 + tid] = r0.x + r1.x + r2.x + r3.x;
            N[(size_t)bj * BN + i0 + tid] = r0.y + r1.y + r2.y + r3.y;
        } else if (tid < 256 && !diag) {
            int c2 = tid - 128;
            float2 a = colSum[0][c2], b = colSum[1][c2];
            P[(size_t)bi * BN + j0 + c2] = a.x + b.x;
            N[(size_t)bi * BN + j0 + c2] = a.y + b.y;
        }

        if (!hasNext) break;

        // Advance to next tile: reload labels (old label reads certified
        // by the pre-combine barrier), histogram, new B pointers + B0.
        t = t2; bi = bi2; bj = bj2; i0 = i02; j0 = j02;
        diag = (bi == bj);
        gA = gA2;
        if (tid < 128)        labI[tid]       = labels[i0 + tid];
        else if (tid < 256)   labJ[tid - 128] = labels[j0 + tid - 128];
        if (diag && tid < 128) atomicAdd(&cntG[labels[i0 + tid]], 1);
        #pragma unroll
        for (int tj = 0; tj < 2; ++tj)
            bptr[tj] = (const v4i*)(E +
                (size_t)(j0 + j_w + tj * 16 + lrow) * DIM + quad * 32);
        __builtin_amdgcn_sched_barrier(0);
        #pragma unroll
        for (int tj = 0; tj < 2; ++tj) {
            ((v4i*)&bf[0][tj])[0] = bptr[tj][0];
            ((v4i*)&bf[0][tj])[1] = bptr[tj][1];
        }
        // vmcnt(4): B0 (4 newest) in flight; all staging for this tile,
        // epilogue stores, and the histogram atomic are retired.
        asm volatile("s_waitcnt vmcnt(4) lgkmcnt(0)" ::: "memory");
        __builtin_amdgcn_s_barrier();
        __builtin_amdgcn_sched_barrier(0);
    }
}

// Fused tail: 128 blocks x 256. Each block owns 64 rows; the 4 waves split
// the 64 column-blocks (16 strided, coalesced 256B/wave), LDS combine,
// per-row loss (histogram read from precomputed global cnt), one
// atomicAdd of the pre-scaled block sum into out[0].
__global__ __launch_bounds__(256) void reduce_finalize_kernel(
        const int* __restrict__ labels, const float* __restrict__ P,
        const float* __restrict__ N, const int* __restrict__ cntG,
        float* __restrict__ out) {
    __shared__ float2 buf[4][64];
    int tid = threadIdx.x;
    int r = tid & 63, w = tid >> 6;
    int i = blockIdx.x * 64 + r;
    float p = 0.f, n = 0.f;
    #pragma unroll
    for (int u = 0; u < 16; ++u) {
        int c = w + u * 4;
        p += P[(size_t)c * BN + i];
        n += N[(size_t)c * BN + i];
    }
    buf[w][r] = (float2){p, n};
    __syncthreads();
    if (tid < 64) {
        float2 s0 = buf[0][r], s1 = buf[1][r], s2 = buf[2][r], s3 = buf[3][r];
        p = s0.x + s1.x + s2.x + s3.x;
        n = s0.y + s1.y + s2.y + s3.y;
        int   cl = cntG[labels[i]];
        float pm = p / fmaxf((float)(cl - 1), 1.0f);
        float nm = n / fmaxf((float)(BN - cl), 1.0f);
        float v  = ((cl - 1 > 0) && (BN - cl > 0))
                       ? -logf(pm / (pm + nm + EPSF)) : 0.0f;
        v *= (1.0f / (float)BN);
        #pragma unroll
        for (int m = 1; m < 64; m <<= 1) v += __shfl_xor(v, m, 64);
        if (r == 0) atomicAdd(out, v);
    }
}

extern "C" void kernel_launch(void* const* d_in, const int* in_sizes, int n_in,
                              void* d_out, int out_size, void* d_ws, size_t ws_size,
                              hipStream_t stream) {
    const float* emb   = (const float*)d_in[0];
    const int* labels  = (const int*)d_in[1];
    float* out         = (float*)d_out;

    // ws layout: E (8 MB reserved; fp8 uses 4, cnt lives at +4 MB) |
    // P (2 MB) | N (2 MB)
    unsigned char* E   = (unsigned char*)d_ws;
    int* cntG          = (int*)((char*)d_ws + (size_t)BN * DIM);
    float* P           = (float*)((char*)d_ws + (size_t)BN * DIM * 2);
    float* N           = P + (size_t)NB * BN;

    normalize_kernel<<<BN / 4, 256, 0, stream>>>(emb, E, cntG, out);
    gemm_epi_kernel<<<PBLK, 512, 0, stream>>>(E, labels, cntG, P, N);
    reduce_finalize_kernel<<<128, 256, 0, stream>>>(labels, P, N, cntG, out);
}

// Round 11
// 115.027 us; speedup vs baseline: 2.3550x; 2.3550x over previous
//
#include <hip/hip_runtime.h>
#include <hip/hip_bf16.h>

#define BN 8192
#define DIM 512
#define NB  64            // BN / 128 block-rows
#define NTILES 2080       // NB*(NB+1)/2 upper-triangle tiles
#define EPSF 1e-8f

using v8i   = __attribute__((ext_vector_type(8))) int;
using v4i   = __attribute__((ext_vector_type(4))) int;
using f32x4 = __attribute__((ext_vector_type(4))) float;
using f32x2 = __attribute__((ext_vector_type(2))) float;

// Native exp2 (single v_exp_f32); fallback keeps exact semantics.
#if __has_builtin(__builtin_amdgcn_exp2f)
#define EXP2F(x) __builtin_amdgcn_exp2f(x)
#else
#define EXP2F(x) __expf((x) * 0.69314718055994531f)
#endif

// Async global->LDS, 16 B per lane, dest = uniform base + lane*16.
__device__ __forceinline__ void async_copy16(const void* g, void* l) {
    __builtin_amdgcn_global_load_lds(
        (const __attribute__((address_space(1))) void*)g,
        (__attribute__((address_space(3))) void*)l,
        16, 0, 0);
}

// One wave per row: L2-normalize, x4 pre-scale, fp8 e4m3; out[0] and the
// global label-count array zeroed by block 0 (cnt is filled by gemm's diag
// blocks, read by finalize -- all stream-ordered).
__global__ __launch_bounds__(256) void normalize_kernel(
        const float* __restrict__ emb, unsigned char* __restrict__ E,
        int* __restrict__ cntG, float* __restrict__ out) {
    if (blockIdx.x == 0) {
        if (threadIdx.x == 0) out[0] = 0.f;
        if (threadIdx.x < 128) cntG[threadIdx.x] = 0;
    }
    int lane = threadIdx.x & 63;
    int row  = blockIdx.x * 4 + (threadIdx.x >> 6);
    const float4* src = (const float4*)(emb + (size_t)row * DIM);
    float4 a = src[lane];
    float4 b = src[lane + 64];
    float ss = a.x*a.x + a.y*a.y + a.z*a.z + a.w*a.w
             + b.x*b.x + b.y*b.y + b.z*b.z + b.w*b.w;
    #pragma unroll
    for (int m = 1; m < 64; m <<= 1) ss += __shfl_xor(ss, m, 64);
    float s4 = 4.0f / fmaxf(sqrtf(ss), 1e-12f);
    int pa = __builtin_amdgcn_cvt_pk_fp8_f32(a.x*s4, a.y*s4, 0, false);
    pa     = __builtin_amdgcn_cvt_pk_fp8_f32(a.z*s4, a.w*s4, pa, true);
    int pb = __builtin_amdgcn_cvt_pk_fp8_f32(b.x*s4, b.y*s4, 0, false);
    pb     = __builtin_amdgcn_cvt_pk_fp8_f32(b.z*s4, b.w*s4, pb, true);
    unsigned char* rowp = E + (size_t)row * DIM;
    ((unsigned*)rowp)[lane]         = (unsigned)pa;
    ((unsigned*)(rowp + 256))[lane] = (unsigned)pb;
}

// Upper-triangle 128x128 tiles, 1D grid (2080), triangular decode.
// fp8 MX MFMA 16x16x128. 512-thread blocks (8 waves), wave (vC,vQ) owns a
// 64x32 output (4x2 of 16x16). Round-6 proven structure: whole-tile A
// staging (4 planes, 64 KB), ONE barrier (counted vmcnt(4)), barrier-free
// k-loop with B register-double-buffered (r8's deeper prefetch + setprio
// and r10's persistence all REGRESSED -- do not reintroduce).
// Round-11 tweak: epilogue accumulates (pos, total) and column sums as
// f32x2 pairs so the compiler emits packed v_pk_add_f32 (gfx90a+ dual-f32
// VALU), cutting ~8 -> ~6 VALU ops per element on the largest busy pipe
// (VALUBusy 27%). Register-neutral.
__global__ __launch_bounds__(512, 4) void gemm_epi_kernel(
        const unsigned char* __restrict__ E, const int* __restrict__ labels,
        int* __restrict__ cntG, float* __restrict__ P, float* __restrict__ N) {
    // smem: A 4-plane (65536 B) overlaid with rowBuf [4][128][17]f2
    // (69632 B) + colBuf [4][2][128]f2 (8192 B) = 77824 B union.
    __shared__ __attribute__((aligned(16))) unsigned char smem[77824];
    __shared__ int labI[128];
    __shared__ int labJ[128];

    int t  = blockIdx.x;
    int bi = (int)(64.5f - sqrtf(64.5f * 64.5f - 2.0f * (float)t));
    while (64 * (bi + 1) - ((bi + 1) * bi) / 2 <= t) ++bi;
    while (64 * bi - (bi * (bi - 1)) / 2 > t) --bi;
    int bj = bi + (t - (64 * bi - (bi * (bi - 1)) / 2));
    const bool diag = (bi == bj);
    const int i0 = bi * 128;
    const int j0 = bj * 128;

    const int tid  = threadIdx.x;
    const int wave = tid >> 6;          // 0..7
    const int lane = tid & 63;
    const int quad = lane >> 4;
    const int lrow = lane & 15;
    const int vC   = wave >> 2;         // i-half   (0..1)
    const int vQ   = wave & 3;          // j-quarter(0..3)
    const int i_w  = vC * 64;
    const int j_w  = vQ * 32;

    if (tid < 128)        labI[tid]       = labels[i0 + tid];
    else if (tid < 256)   labJ[tid - 128] = labels[j0 + tid - 128];
    // Diag blocks build the global label histogram (64 blocks x 128 rows
    // covers every row exactly once). Retired by the prologue vmcnt.
    if (diag && tid < 128) atomicAdd(&cntG[labels[i0 + tid]], 1);

    unsigned char* As = smem;                     // [4][128][128] planes
    float2* rowBuf = (float2*)smem;               // [4][128][17]
    float2* colBuf = (float2*)(smem + 69632);     // [4][2][128]

    f32x4 acc[4][2];
    #pragma unroll
    for (int a = 0; a < 4; ++a)
        #pragma unroll
        for (int b = 0; b < 2; ++b)
            acc[a][b] = (f32x4){0.f, 0.f, 0.f, 0.f};

    const v4i* bptr[2];
    #pragma unroll
    for (int tj = 0; tj < 2; ++tj)
        bptr[tj] = (const v4i*)(E +
            (size_t)(j0 + j_w + tj * 16 + lrow) * DIM + quad * 32);

    // Staging lane constants: each wave covers rows [wave*16, wave*16+16),
    // 2 instrs x 8 rows per plane; lane l -> row (l>>3), LDS chunk l&7
    // holds global chunk (l&7)^(l>>3) (row&7 == l>>3, bases multiple of 8).
    const int stRow = lane >> 3;
    const int stChk = (lane & 7) ^ stRow;
    const unsigned char* gA = E + (size_t)(i0 + wave * 16 + stRow) * DIM
                                + stChk * 16;
    const int sw = lrow & 7;

    // Prologue: stage ALL 4 A-planes (8 instrs/wave), then B(0) prefetch
    // (4 instrs). vmcnt(4): staging fully retired (older than B0),
    // B0 still in flight. lgkmcnt(0) drains the label ds_writes.
    #pragma unroll
    for (int c = 0; c < 4; ++c)
        #pragma unroll
        for (int h = 0; h < 2; ++h)
            async_copy16(gA + (size_t)h * 8 * DIM + c * 128,
                         As + (size_t)c * 16384
                            + (size_t)(wave * 16 + h * 8) * 128);
    __builtin_amdgcn_sched_barrier(0);   // keep staging before B loads

    v8i bf[2][2];
    #pragma unroll
    for (int tj = 0; tj < 2; ++tj) {      // prefetch B for k=0
        ((v4i*)&bf[0][tj])[0] = bptr[tj][0];
        ((v4i*)&bf[0][tj])[1] = bptr[tj][1];
    }
    asm volatile("s_waitcnt vmcnt(4) lgkmcnt(0)" ::: "memory");
    __builtin_amdgcn_s_barrier();
    // ---- from here to the epilogue sync: NO barriers, NO staging ----

    #pragma unroll
    for (int k = 0; k < 4; ++k) {
        const int cur = k & 1;
        const unsigned char* bufC = As + (size_t)k * 16384;
        v8i af[4];
        #pragma unroll
        for (int ti = 0; ti < 4; ++ti) {
            int r  = i_w + ti * 16 + lrow;
            const v4i* rp = (const v4i*)(bufC + (size_t)r * 128);
            ((v4i*)&af[ti])[0] = rp[(quad * 2) ^ sw];
            ((v4i*)&af[ti])[1] = rp[(quad * 2 + 1) ^ sw];
        }
        if (k < 3) {                      // prefetch next k's B
            #pragma unroll
            for (int tj = 0; tj < 2; ++tj) {
                ((v4i*)&bf[cur ^ 1][tj])[0] = bptr[tj][(k + 1) * 8];
                ((v4i*)&bf[cur ^ 1][tj])[1] = bptr[tj][(k + 1) * 8 + 1];
            }
        }
        #pragma unroll
        for (int ti = 0; ti < 4; ++ti)
            #pragma unroll
            for (int tj = 0; tj < 2; ++tj)
                acc[ti][tj] =
                    __builtin_amdgcn_mfma_scale_f32_16x16x128_f8f6f4(
                        af[ti], bf[cur][tj], acc[ti][tj],
                        0, 0,                 // fp8 e4m3 / e4m3
                        0, 0x7F7F7F7F,        // A scale = 1.0
                        0, 0x7F7F7F7F);       // B scale = 1.0
    }
    __syncthreads();      // all waves done reading As -> overlay writable

    // Epilogue. C/D: col = lane&15, row = quad*4 + reg. acc = 16*S.
    // w = exp(S-1) = exp2(acc*K1 + K2). 32 elements/thread.
    // (pos, total) accumulated as f32x2 -> packed v_pk_add_f32.
    const float K1 = 0.0901619783824569f;    // log2(e)/16
    const float K2 = -1.4426950408889634f;   // -log2(e)
    if (!diag) {
        f32x2 cs[2];
        cs[0] = (f32x2){0.f, 0.f};
        cs[1] = (f32x2){0.f, 0.f};
        #pragma unroll
        for (int ti = 0; ti < 4; ++ti) {
            #pragma unroll
            for (int reg = 0; reg < 4; ++reg) {
                int irow = i_w + ti * 16 + quad * 4 + reg;
                int li   = labI[irow];
                f32x2 pt = (f32x2){0.f, 0.f};      // (pos, total)
                #pragma unroll
                for (int tj = 0; tj < 2; ++tj) {
                    int jcol = j_w + tj * 16 + lrow;
                    float w  = EXP2F(fmaf(acc[ti][tj][reg], K1, K2));
                    f32x2 wv;
                    wv[0] = (li == labJ[jcol]) ? w : 0.f;
                    wv[1] = w;
                    pt += wv;
                    cs[tj] += wv;
                }
                rowBuf[(size_t)(vQ * 128 + irow) * 17 + lrow] =
                    (float2){pt[0], pt[1] - pt[0]};
            }
        }
        #pragma unroll
        for (int tj = 0; tj < 2; ++tj) {
            int jcol = j_w + tj * 16 + lrow;
            colBuf[(size_t)(quad * 2 + vC) * 128 + jcol] =
                (float2){cs[tj][0], cs[tj][1] - cs[tj][0]};
        }
    } else {
        // Diag tile: self pair (irow == jcol) excluded from pos exactly;
        // col sums unused (row path covers the full square).
        #pragma unroll
        for (int ti = 0; ti < 4; ++ti) {
            #pragma unroll
            for (int reg = 0; reg < 4; ++reg) {
                int irow = i_w + ti * 16 + quad * 4 + reg;
                int li   = labI[irow];
                f32x2 pt = (f32x2){0.f, 0.f};      // (pos, total)
                float sf = 0.f;
                #pragma unroll
                for (int tj = 0; tj < 2; ++tj) {
                    int jcol = j_w + tj * 16 + lrow;
                    float w  = EXP2F(fmaf(acc[ti][tj][reg], K1, K2));
                    f32x2 wv;
                    wv[0] = (li == labJ[jcol]) ? w : 0.f;
                    wv[1] = w;
                    pt += wv;
                    sf += (irow == jcol) ? w : 0.f;
                }
                rowBuf[(size_t)(vQ * 128 + irow) * 17 + lrow] =
                    (float2){pt[0] - sf, pt[1] - pt[0]};
            }
        }
    }
    __syncthreads();

    if (tid < 128) {
        float sp = 0.f, sn = 0.f;
        #pragma unroll
        for (int vq = 0; vq < 4; ++vq) {
            const float2* a = rowBuf + (size_t)(vq * 128 + tid) * 17;
            #pragma unroll
            for (int u = 0; u < 16; ++u) {
                sp += a[u].x;
                sn += a[u].y;
            }
        }
        P[(size_t)bj * BN + i0 + tid] = sp;
        N[(size_t)bj * BN + i0 + tid] = sn;
    } else if (tid < 256 && !diag) {
        int c2 = tid - 128;
        float sp = 0.f, sn = 0.f;
        #pragma unroll
        for (int s = 0; s < 8; ++s) {
            float2 a = colBuf[(size_t)s * 128 + c2];
            sp += a.x;
            sn += a.y;
        }
        P[(size_t)bi * BN + j0 + c2] = sp;
        N[(size_t)bi * BN + j0 + c2] = sn;
    }
}

// Fused tail: 128 blocks x 256. Each block owns 64 rows; the 4 waves split
// the 64 column-blocks (16 strided, coalesced 256B/wave), LDS combine,
// per-row loss (histogram read from precomputed global cnt), one
// atomicAdd of the pre-scaled block sum into out[0].
__global__ __launch_bounds__(256) void reduce_finalize_kernel(
        const int* __restrict__ labels, const float* __restrict__ P,
        const float* __restrict__ N, const int* __restrict__ cntG,
        float* __restrict__ out) {
    __shared__ float2 buf[4][64];
    int tid = threadIdx.x;
    int r = tid & 63, w = tid >> 6;
    int i = blockIdx.x * 64 + r;
    float p = 0.f, n = 0.f;
    #pragma unroll
    for (int u = 0; u < 16; ++u) {
        int c = w + u * 4;
        p += P[(size_t)c * BN + i];
        n += N[(size_t)c * BN + i];
    }
    buf[w][r] = (float2){p, n};
    __syncthreads();
    if (tid < 64) {
        float2 s0 = buf[0][r], s1 = buf[1][r], s2 = buf[2][r], s3 = buf[3][r];
        p = s0.x + s1.x + s2.x + s3.x;
        n = s0.y + s1.y + s2.y + s3.y;
        int   cl = cntG[labels[i]];
        float pm = p / fmaxf((float)(cl - 1), 1.0f);
        float nm = n / fmaxf((float)(BN - cl), 1.0f);
        float v  = ((cl - 1 > 0) && (BN - cl > 0))
                       ? -logf(pm / (pm + nm + EPSF)) : 0.0f;
        v *= (1.0f / (float)BN);
        #pragma unroll
        for (int m = 1; m < 64; m <<= 1) v += __shfl_xor(v, m, 64);
        if (r == 0) atomicAdd(out, v);
    }
}

extern "C" void kernel_launch(void* const* d_in, const int* in_sizes, int n_in,
                              void* d_out, int out_size, void* d_ws, size_t ws_size,
                              hipStream_t stream) {
    const float* emb   = (const float*)d_in[0];
    const int* labels  = (const int*)d_in[1];
    float* out         = (float*)d_out;

    // ws layout: E (8 MB reserved; fp8 uses 4, cnt lives at +4 MB) |
    // P (2 MB) | N (2 MB)
    unsigned char* E   = (unsigned char*)d_ws;
    int* cntG          = (int*)((char*)d_ws + (size_t)BN * DIM);
    float* P           = (float*)((char*)d_ws + (size_t)BN * DIM * 2);
    float* N           = P + (size_t)NB * BN;

    normalize_kernel<<<BN / 4, 256, 0, stream>>>(emb, E, cntG, out);
    gemm_epi_kernel<<<NTILES, 512, 0, stream>>>(E, labels, cntG, P, N);
    reduce_finalize_kernel<<<128, 256, 0, stream>>>(labels, P, N, cntG, out);
}

// Round 14
// 113.864 us; speedup vs baseline: 2.3791x; 1.0102x over previous
//
#include <hip/hip_runtime.h>
#include <hip/hip_bf16.h>

#define BN 8192
#define DIM 512
#define NB  64            // BN / 128 block-rows
#define NTILES 2080       // NB*(NB+1)/2 upper-triangle tiles
#define EPSF 1e-8f

using v8i   = __attribute__((ext_vector_type(8))) int;
using v4i   = __attribute__((ext_vector_type(4))) int;
using f32x4 = __attribute__((ext_vector_type(4))) float;
using f32x2 = __attribute__((ext_vector_type(2))) float;

// Native exp2 (single v_exp_f32); fallback keeps exact semantics.
#if __has_builtin(__builtin_amdgcn_exp2f)
#define EXP2F(x) __builtin_amdgcn_exp2f(x)
#else
#define EXP2F(x) __expf((x) * 0.69314718055994531f)
#endif

// Async global->LDS, 16 B per lane, dest = uniform base + lane*16.
__device__ __forceinline__ void async_copy16(const void* g, void* l) {
    __builtin_amdgcn_global_load_lds(
        (const __attribute__((address_space(1))) void*)g,
        (__attribute__((address_space(3))) void*)l,
        16, 0, 0);
}

// One wave per row: L2-normalize, x4 pre-scale, fp8 e4m3; out[0] and the
// global label-count array zeroed by block 0 (cnt is filled by gemm's diag
// blocks, read by finalize -- all stream-ordered).
__global__ __launch_bounds__(256) void normalize_kernel(
        const float* __restrict__ emb, unsigned char* __restrict__ E,
        int* __restrict__ cntG, float* __restrict__ out) {
    if (blockIdx.x == 0) {
        if (threadIdx.x == 0) out[0] = 0.f;
        if (threadIdx.x < 128) cntG[threadIdx.x] = 0;
    }
    int lane = threadIdx.x & 63;
    int row  = blockIdx.x * 4 + (threadIdx.x >> 6);
    const float4* src = (const float4*)(emb + (size_t)row * DIM);
    float4 a = src[lane];
    float4 b = src[lane + 64];
    float ss = a.x*a.x + a.y*a.y + a.z*a.z + a.w*a.w
             + b.x*b.x + b.y*b.y + b.z*b.z + b.w*b.w;
    #pragma unroll
    for (int m = 1; m < 64; m <<= 1) ss += __shfl_xor(ss, m, 64);
    float s4 = 4.0f / fmaxf(sqrtf(ss), 1e-12f);
    int pa = __builtin_amdgcn_cvt_pk_fp8_f32(a.x*s4, a.y*s4, 0, false);
    pa     = __builtin_amdgcn_cvt_pk_fp8_f32(a.z*s4, a.w*s4, pa, true);
    int pb = __builtin_amdgcn_cvt_pk_fp8_f32(b.x*s4, b.y*s4, 0, false);
    pb     = __builtin_amdgcn_cvt_pk_fp8_f32(b.z*s4, b.w*s4, pb, true);
    unsigned char* rowp = E + (size_t)row * DIM;
    ((unsigned*)rowp)[lane]         = (unsigned)pa;
    ((unsigned*)(rowp + 256))[lane] = (unsigned)pb;
}

// Upper-triangle 128x128 tiles, 1D grid (2080), triangular decode.
// fp8 MX MFMA 16x16x128. 512-thread blocks (8 waves), wave (vC,vQ) owns a
// 64x32 output (4x2 of 16x16). Round-6/11 structure with one change:
// B0 is issued BEFORE the A staging. vmcnt retires IN ORDER, so in r6/r11
// the compiler's wait for B0 (issued after staging) forced the full 64 KB
// A-drain before the first MFMA -- the counted vmcnt(4) never overlapped
// anything. With B0 oldest: k-step 0 starts after only plane 0 is staged
// (vmcnt(6)); planes 1-3 drain UNDER k0-k2's compute and are certified by
// cheap counted waits + barriers at each k-top (vmcnt(8)/(6)/(4)).
// Exposed prologue: 64 KB-drain -> ~20 KB-drain. This sync class (raw
// s_barrier + counted inline-asm vmcnt in the k-loop) is proven runnable
// on this toolchain (rounds 1/4/5). Epilogue = r11 (f32x2 packed adds).
// Do NOT reintroduce: deeper B prefetch/setprio (r8 regressed),
// persistence (r10 scratch-spilled), global atomics (r9 +18us).
__global__ __launch_bounds__(512, 4) void gemm_epi_kernel(
        const unsigned char* __restrict__ E, const int* __restrict__ labels,
        int* __restrict__ cntG, float* __restrict__ P, float* __restrict__ N) {
    // smem: A 4-plane (65536 B) overlaid with rowBuf [4][128][17]f2
    // (69632 B) + colBuf [4][2][128]f2 (8192 B) = 77824 B union.
    __shared__ __attribute__((aligned(16))) unsigned char smem[77824];
    __shared__ int labI[128];
    __shared__ int labJ[128];

    int t  = blockIdx.x;
    int bi = (int)(64.5f - sqrtf(64.5f * 64.5f - 2.0f * (float)t));
    while (64 * (bi + 1) - ((bi + 1) * bi) / 2 <= t) ++bi;
    while (64 * bi - (bi * (bi - 1)) / 2 > t) --bi;
    int bj = bi + (t - (64 * bi - (bi * (bi - 1)) / 2));
    const bool diag = (bi == bj);
    const int i0 = bi * 128;
    const int j0 = bj * 128;

    const int tid  = threadIdx.x;
    const int wave = tid >> 6;          // 0..7
    const int lane = tid & 63;
    const int quad = lane >> 4;
    const int lrow = lane & 15;
    const int vC   = wave >> 2;         // i-half   (0..1)
    const int vQ   = wave & 3;          // j-quarter(0..3)
    const int i_w  = vC * 64;
    const int j_w  = vQ * 32;

    if (tid < 128)        labI[tid]       = labels[i0 + tid];
    else if (tid < 256)   labJ[tid - 128] = labels[j0 + tid - 128];
    // Diag blocks build the global label histogram (64 blocks x 128 rows
    // covers every row exactly once). Oldest VMEM op; retires first, so
    // all counted waits below remain valid for diag and non-diag waves.
    if (diag && tid < 128) atomicAdd(&cntG[labels[i0 + tid]], 1);

    unsigned char* As = smem;                     // [4][128][128] planes
    float2* rowBuf = (float2*)smem;               // [4][128][17]
    float2* colBuf = (float2*)(smem + 69632);     // [4][2][128]

    f32x4 acc[4][2];
    #pragma unroll
    for (int a = 0; a < 4; ++a)
        #pragma unroll
        for (int b = 0; b < 2; ++b)
            acc[a][b] = (f32x4){0.f, 0.f, 0.f, 0.f};

    const v4i* bptr[2];
    #pragma unroll
    for (int tj = 0; tj < 2; ++tj)
        bptr[tj] = (const v4i*)(E +
            (size_t)(j0 + j_w + tj * 16 + lrow) * DIM + quad * 32);

    // Staging lane constants: each wave covers rows [wave*16, wave*16+16),
    // 2 instrs x 8 rows per plane; lane l -> row (l>>3), LDS chunk l&7
    // holds global chunk (l&7)^(l>>3) (row&7 == l>>3, bases multiple of 8).
    const int stRow = lane >> 3;
    const int stChk = (lane & 7) ^ stRow;
    const unsigned char* gA = E + (size_t)(i0 + wave * 16 + stRow) * DIM
                                + stChk * 16;
    const int sw = lrow & 7;

    // Prologue. Issue order (per wave): [atomic?] B0x4, p0..p3 staging x8.
    // B0 oldest among the loop's ops -> its use never forces a staging
    // drain (in-order vmcnt retirement). k0-top wait vmcnt(6): B0 + p0
    // retired; p1-p3 (48 KB) drain under k0-k2 compute.
    v8i bf[2][2];
    #pragma unroll
    for (int tj = 0; tj < 2; ++tj) {      // B0 FIRST
        ((v4i*)&bf[0][tj])[0] = bptr[tj][0];
        ((v4i*)&bf[0][tj])[1] = bptr[tj][1];
    }
    __builtin_amdgcn_sched_barrier(0);   // keep B0 before staging
    #pragma unroll
    for (int c = 0; c < 4; ++c)
        #pragma unroll
        for (int h = 0; h < 2; ++h)
            async_copy16(gA + (size_t)h * 8 * DIM + c * 128,
                         As + (size_t)c * 16384
                            + (size_t)(wave * 16 + h * 8) * 128);
    __builtin_amdgcn_sched_barrier(0);

    #pragma unroll
    for (int k = 0; k < 4; ++k) {
        const int cur = k & 1;
        const unsigned char* bufC = As + (size_t)k * 16384;
        // Certify plane k staged (own waitcnt) across all waves (barrier).
        // Queue at k-top (oldest->new): p(k)..p3 staging | B(k) consumed |
        // B(k+1) in flight (for k>=1). Counted waits, never 0:
        //   k=0: <=6 (p1p2p3)      k=1: <=8 (p2p3 + B1's 4)
        //   k=2: <=6 (p3 + B2)     k=3: <=4 (B3)
        if (k == 0) {
            asm volatile("s_waitcnt vmcnt(6) lgkmcnt(0)" ::: "memory");
        } else if (k == 1) {
            asm volatile("s_waitcnt vmcnt(8)" ::: "memory");
        } else if (k == 2) {
            asm volatile("s_waitcnt vmcnt(6)" ::: "memory");
        } else {
            asm volatile("s_waitcnt vmcnt(4)" ::: "memory");
        }
        __builtin_amdgcn_s_barrier();
        __builtin_amdgcn_sched_barrier(0);

        v8i af[4];
        #pragma unroll
        for (int ti = 0; ti < 4; ++ti) {
            int r  = i_w + ti * 16 + lrow;
            const v4i* rp = (const v4i*)(bufC + (size_t)r * 128);
            ((v4i*)&af[ti])[0] = rp[(quad * 2) ^ sw];
            ((v4i*)&af[ti])[1] = rp[(quad * 2 + 1) ^ sw];
        }
        if (k < 3) {                      // prefetch next k's B
            #pragma unroll
            for (int tj = 0; tj < 2; ++tj) {
                ((v4i*)&bf[cur ^ 1][tj])[0] = bptr[tj][(k + 1) * 8];
                ((v4i*)&bf[cur ^ 1][tj])[1] = bptr[tj][(k + 1) * 8 + 1];
            }
        }
        #pragma unroll
        for (int ti = 0; ti < 4; ++ti)
            #pragma unroll
            for (int tj = 0; tj < 2; ++tj)
                acc[ti][tj] =
                    __builtin_amdgcn_mfma_scale_f32_16x16x128_f8f6f4(
                        af[ti], bf[cur][tj], acc[ti][tj],
                        0, 0,                 // fp8 e4m3 / e4m3
                        0, 0x7F7F7F7F,        // A scale = 1.0
                        0, 0x7F7F7F7F);       // B scale = 1.0
    }
    __syncthreads();      // all waves done reading As -> overlay writable

    // Epilogue. C/D: col = lane&15, row = quad*4 + reg. acc = 16*S.
    // w = exp(S-1) = exp2(acc*K1 + K2). 32 elements/thread.
    // (pos, total) accumulated as f32x2 -> packed v_pk_add_f32.
    const float K1 = 0.0901619783824569f;    // log2(e)/16
    const float K2 = -1.4426950408889634f;   // -log2(e)
    if (!diag) {
        f32x2 cs[2];
        cs[0] = (f32x2){0.f, 0.f};
        cs[1] = (f32x2){0.f, 0.f};
        #pragma unroll
        for (int ti = 0; ti < 4; ++ti) {
            #pragma unroll
            for (int reg = 0; reg < 4; ++reg) {
                int irow = i_w + ti * 16 + quad * 4 + reg;
                int li   = labI[irow];
                f32x2 pt = (f32x2){0.f, 0.f};      // (pos, total)
                #pragma unroll
                for (int tj = 0; tj < 2; ++tj) {
                    int jcol = j_w + tj * 16 + lrow;
                    float w  = EXP2F(fmaf(acc[ti][tj][reg], K1, K2));
                    f32x2 wv;
                    wv[0] = (li == labJ[jcol]) ? w : 0.f;
                    wv[1] = w;
                    pt += wv;
                    cs[tj] += wv;
                }
                rowBuf[(size_t)(vQ * 128 + irow) * 17 + lrow] =
                    (float2){pt[0], pt[1] - pt[0]};
            }
        }
        #pragma unroll
        for (int tj = 0; tj < 2; ++tj) {
            int jcol = j_w + tj * 16 + lrow;
            colBuf[(size_t)(quad * 2 + vC) * 128 + jcol] =
                (float2){cs[tj][0], cs[tj][1] - cs[tj][0]};
        }
    } else {
        // Diag tile: self pair (irow == jcol) excluded from pos exactly;
        // col sums unused (row path covers the full square).
        #pragma unroll
        for (int ti = 0; ti < 4; ++ti) {
            #pragma unroll
            for (int reg = 0; reg < 4; ++reg) {
                int irow = i_w + ti * 16 + quad * 4 + reg;
                int li   = labI[irow];
                f32x2 pt = (f32x2){0.f, 0.f};      // (pos, total)
                float sf = 0.f;
                #pragma unroll
                for (int tj = 0; tj < 2; ++tj) {
                    int jcol = j_w + tj * 16 + lrow;
                    float w  = EXP2F(fmaf(acc[ti][tj][reg], K1, K2));
                    f32x2 wv;
                    wv[0] = (li == labJ[jcol]) ? w : 0.f;
                    wv[1] = w;
                    pt += wv;
                    sf += (irow == jcol) ? w : 0.f;
                }
                rowBuf[(size_t)(vQ * 128 + irow) * 17 + lrow] =
                    (float2){pt[0] - sf, pt[1] - pt[0]};
            }
        }
    }
    __syncthreads();

    if (tid < 128) {
        float sp = 0.f, sn = 0.f;
        #pragma unroll
        for (int vq = 0; vq < 4; ++vq) {
            const float2* a = rowBuf + (size_t)(vq * 128 + tid) * 17;
            #pragma unroll
            for (int u = 0; u < 16; ++u) {
                sp += a[u].x;
                sn += a[u].y;
            }
        }
        P[(size_t)bj * BN + i0 + tid] = sp;
        N[(size_t)bj * BN + i0 + tid] = sn;
    } else if (tid < 256 && !diag) {
        int c2 = tid - 128;
        float sp = 0.f, sn = 0.f;
        #pragma unroll
        for (int s = 0; s < 8; ++s) {
            float2 a = colBuf[(size_t)s * 128 + c2];
            sp += a.x;
            sn += a.y;
        }
        P[(size_t)bi * BN + j0 + c2] = sp;
        N[(size_t)bi * BN + j0 + c2] = sn;
    }
}

// Fused tail: 128 blocks x 256. Each block owns 64 rows; the 4 waves split
// the 64 column-blocks (16 strided, coalesced 256B/wave), LDS combine,
// per-row loss (histogram read from precomputed global cnt), one
// atomicAdd of the pre-scaled block sum into out[0].
__global__ __launch_bounds__(256) void reduce_finalize_kernel(
        const int* __restrict__ labels, const float* __restrict__ P,
        const float* __restrict__ N, const int* __restrict__ cntG,
        float* __restrict__ out) {
    __shared__ float2 buf[4][64];
    int tid = threadIdx.x;
    int r = tid & 63, w = tid >> 6;
    int i = blockIdx.x * 64 + r;
    float p = 0.f, n = 0.f;
    #pragma unroll
    for (int u = 0; u < 16; ++u) {
        int c = w + u * 4;
        p += P[(size_t)c * BN + i];
        n += N[(size_t)c * BN + i];
    }
    buf[w][r] = (float2){p, n};
    __syncthreads();
    if (tid < 64) {
        float2 s0 = buf[0][r], s1 = buf[1][r], s2 = buf[2][r], s3 = buf[3][r];
        p = s0.x + s1.x + s2.x + s3.x;
        n = s0.y + s1.y + s2.y + s3.y;
        int   cl = cntG[labels[i]];
        float pm = p / fmaxf((float)(cl - 1), 1.0f);
        float nm = n / fmaxf((float)(BN - cl), 1.0f);
        float v  = ((cl - 1 > 0) && (BN - cl > 0))
                       ? -logf(pm / (pm + nm + EPSF)) : 0.0f;
        v *= (1.0f / (float)BN);
        #pragma unroll
        for (int m = 1; m < 64; m <<= 1) v += __shfl_xor(v, m, 64);
        if (r == 0) atomicAdd(out, v);
    }
}

extern "C" void kernel_launch(void* const* d_in, const int* in_sizes, int n_in,
                              void* d_out, int out_size, void* d_ws, size_t ws_size,
                              hipStream_t stream) {
    const float* emb   = (const float*)d_in[0];
    const int* labels  = (const int*)d_in[1];
    float* out         = (float*)d_out;

    // ws layout: E (8 MB reserved; fp8 uses 4, cnt lives at +4 MB) |
    // P (2 MB) | N (2 MB)
    unsigned char* E   = (unsigned char*)d_ws;
    int* cntG          = (int*)((char*)d_ws + (size_t)BN * DIM);
    float* P           = (float*)((char*)d_ws + (size_t)BN * DIM * 2);
    float* N           = P + (size_t)NB * BN;

    normalize_kernel<<<BN / 4, 256, 0, stream>>>(emb, E, cntG, out);
    gemm_epi_kernel<<<NTILES, 512, 0, stream>>>(E, labels, cntG, P, N);
    reduce_finalize_kernel<<<128, 256, 0, stream>>>(labels, P, N, cntG, out);
}